// Round 7
// baseline (276.628 us; speedup 1.0000x reference)
//
#include <hip/hip_runtime.h>
#include <math.h>

#define DD 2048
#define EE 64
#define TM 32                 // tokens per block; grid = 512 -> 2 blocks/CU
#define THREADS 512           // 8 waves: 2 token-tiles x 4 expert-tiles
#define KSTEPS (DD / 32)      // 64 MFMA K-steps

typedef _Float16 f16x8 __attribute__((ext_vector_type(8)));
typedef float    f32x4 __attribute__((ext_vector_type(4)));

// split 8 consecutive f32 (scaled by 32) into f16 hi + f16 lo planes
__device__ static inline void split8(const float4 a, const float4 b,
                                     f16x8& hi, f16x8& lo) {
    const float S = 32.f;     // keeps lo parts out of f16 subnormal flush range
    const float v[8] = {a.x * S, a.y * S, a.z * S, a.w * S,
                        b.x * S, b.y * S, b.z * S, b.w * S};
#pragma unroll
    for (int i = 0; i < 8; ++i) {
        const _Float16 h = (_Float16)v[i];
        hi[i] = h;
        lo[i] = (_Float16)(v[i] - (float)h);
    }
}

// prologue: W (f32 [E][D]) -> f16 hi/lo planes [E][D] in workspace
__global__ __launch_bounds__(256) void wsplit_kernel(
    const float* __restrict__ W, _Float16* __restrict__ whi,
    _Float16* __restrict__ wlo)
{
    const int i = (blockIdx.x * 256 + threadIdx.x) * 8;
    const float4 a = *(const float4*)&W[i];
    const float4 b = *(const float4*)&W[i + 4];
    f16x8 hi, lo;
    split8(a, b, hi, lo);
    *(f16x8*)&whi[i] = hi;
    *(f16x8*)&wlo[i] = lo;
}

// main: barrier-free, LDS-free K-loop; fragments loaded direct from global.
// A-frag: lane = 8 consecutive k of token row (x is row-major: direct b128).
// B-frag: lane = 8 consecutive k of expert row (whi/wlo planes: direct b128).
__global__ __launch_bounds__(THREADS, 4) void router_kernel(
    const float* __restrict__ x, const _Float16* __restrict__ whi,
    const _Float16* __restrict__ wlo, const float* __restrict__ bias_g,
    float* __restrict__ out, int n_tokens)
{
    __shared__ __attribute__((aligned(16))) float logits[TM * (EE + 1)];

    const int tid   = threadIdx.x;
    const int tBase = blockIdx.x * TM;

    const int wv   = tid >> 6;        // wave 0..7
    const int lane = tid & 63;
    const int mt   = wv & 1;          // token tile (16 tokens)
    const int nt   = wv >> 1;         // expert tile 0..3
    const int r16  = lane & 15;
    const int kg   = lane >> 4;       // k-group: k = kg*8 + j

    const float*    xr  = x   + (size_t)(tBase + mt * 16 + r16) * DD + kg * 8;
    const _Float16* bhp = whi + (size_t)(nt * 16 + r16) * DD + kg * 8;
    const _Float16* blp = wlo + (size_t)(nt * 16 + r16) * DD + kg * 8;

    f32x4 acc = {0.f, 0.f, 0.f, 0.f};

    // two register stages (named -> all indices compile-time, no scratch)
    float4 a0A, a1A; f16x8 bhA, blA;
    float4 a0B, a1B; f16x8 bhB, blB;

#define LOADK(t, a0, a1, bh, bl) { \
    const int k0 = (t) * 32; \
    a0 = *(const float4*)&xr[k0]; \
    a1 = *(const float4*)&xr[k0 + 4]; \
    bh = *(const f16x8*)&bhp[k0]; \
    bl = *(const f16x8*)&blp[k0]; }

    // 3-product split (skip lo*lo: ~2^-22 rel, negligible; verified absmax 0)
#define CONSUME(a0, a1, bh, bl) { \
    f16x8 ah, al; split8(a0, a1, ah, al); \
    acc = __builtin_amdgcn_mfma_f32_16x16x32_f16(ah, bh, acc, 0, 0, 0); \
    acc = __builtin_amdgcn_mfma_f32_16x16x32_f16(al, bh, acc, 0, 0, 0); \
    acc = __builtin_amdgcn_mfma_f32_16x16x32_f16(ah, bl, acc, 0, 0, 0); }

    LOADK(0, a0A, a1A, bhA, blA);
    LOADK(1, a0B, a1B, bhB, blB);

    for (int t = 0; t < KSTEPS; t += 2) {
        CONSUME(a0A, a1A, bhA, blA);                       // K-step t
        if (t + 2 < KSTEPS) LOADK(t + 2, a0A, a1A, bhA, blA);
        CONSUME(a0B, a1B, bhB, blB);                       // K-step t+1
        if (t + 3 < KSTEPS) LOADK(t + 3, a0B, a1B, bhB, blB);
    }

    // ---- epilogue: unscale (acc = 1024 * logit), add bias, top-2 ----
    const int col  = nt * 16 + r16;
    const float bcol = bias_g[col];
    const float INV  = 1.f / 1024.f;
    const int rbase  = mt * 16 + kg * 4;
#pragma unroll
    for (int r = 0; r < 4; ++r)
        logits[(rbase + r) * (EE + 1) + col] = acc[r] * INV + bcol;
    __syncthreads();

    if (tid < TM) {
        const float* lrow = &logits[tid * (EE + 1)];
        float v1 = -INFINITY, v2 = -INFINITY;
        int   i1 = 0, i2 = 0;
        for (int e = 0; e < EE; ++e) {
            const float v = lrow[e];
            if (v > v1) { v2 = v1; i2 = i1; v1 = v; i1 = e; }
            else if (v > v2) { v2 = v; i2 = e; }
        }
        const float ed  = expf(v2 - v1);
        const float inv = 1.f / (1.f + ed);
        const int tok = tBase + tid;
        out[tok * 2 + 0] = inv;
        out[tok * 2 + 1] = ed * inv;
        float* oidx = out + (size_t)2 * n_tokens;
        oidx[tok * 2 + 0] = (float)i1;
        oidx[tok * 2 + 1] = (float)i2;
    }
}

extern "C" void kernel_launch(void* const* d_in, const int* in_sizes, int n_in,
                              void* d_out, int out_size, void* d_ws, size_t ws_size,
                              hipStream_t stream) {
    const float* x = (const float*)d_in[0];
    const float* W = (const float*)d_in[1];
    const float* b = (const float*)d_in[2];
    float* out = (float*)d_out;

    const int n_tokens = in_sizes[0] / DD;      // 16384
    const int n_blocks = n_tokens / TM;         // 512

    _Float16* whi = (_Float16*)d_ws;
    _Float16* wlo = whi + (size_t)EE * DD;      // 256 KB each, ws is plenty

    wsplit_kernel<<<(EE * DD) / (256 * 8), 256, 0, stream>>>(W, whi, wlo);
    router_kernel<<<n_blocks, THREADS, 0, stream>>>(x, whi, wlo, b, out, n_tokens);
}

// Round 8
// 202.251 us; speedup vs baseline: 1.3677x; 1.3677x over previous
//
#include <hip/hip_runtime.h>
#include <math.h>

#define DD 2048
#define EE 64
#define TM 32                 // tokens per block; grid = 512 -> 2 blocks/CU
#define BK 64                 // K per chunk (2 MFMA K-steps)
#define NCHUNK (DD / BK)      // 32
#define THREADS 512           // 8 waves: 2 token-tiles x 4 expert-tiles

// LDS row layout: per 8-k group g: [hi(8 f16) 16B][lo(8 f16) 16B] at byte 32*g.
// ROWB = 8*32 + 16 pad = 272 -> b128 reads/writes spread 8-per-bank (floor).
#define ROWB 272
#define XPLANE (TM * ROWB)        // 8704 B
#define WPLANE (EE * ROWB)        // 17408 B
#define BUFB   (XPLANE + WPLANE)  // 26112 B per buffer

// W pre-split global layout: [E][256 groups][hi 16B | lo 16B], row = 8192 B
#define WROWB 8192

typedef _Float16 f16x8 __attribute__((ext_vector_type(8)));
typedef _Float16 f16x4 __attribute__((ext_vector_type(4)));
typedef float    f32x4 __attribute__((ext_vector_type(4)));

// lgkm-only barrier: drains LDS ops (cross-wave visibility) but leaves global
// loads (wave-private reg dests) in flight across the barrier.
#define BARRIER() { asm volatile("s_waitcnt lgkmcnt(0)" ::: "memory"); \
                    __builtin_amdgcn_s_barrier(); \
                    __builtin_amdgcn_sched_barrier(0); }

__device__ static inline void split8(const float4 a, const float4 b,
                                     f16x8& hi, f16x8& lo) {
    const float S = 32.f;     // keeps lo parts out of f16 subnormal flush range
    const float v[8] = {a.x * S, a.y * S, a.z * S, a.w * S,
                        b.x * S, b.y * S, b.z * S, b.w * S};
#pragma unroll
    for (int i = 0; i < 8; ++i) {
        const _Float16 h = (_Float16)v[i];
        hi[i] = h;
        lo[i] = (_Float16)(v[i] - (float)h);
    }
}

__device__ static inline void split4(const float4 v, f16x4& hi, f16x4& lo) {
    const float S = 32.f;
    const float a0 = v.x * S, a1 = v.y * S, a2 = v.z * S, a3 = v.w * S;
    const _Float16 h0 = (_Float16)a0, h1 = (_Float16)a1;
    const _Float16 h2 = (_Float16)a2, h3 = (_Float16)a3;
    hi = (f16x4){h0, h1, h2, h3};
    lo = (f16x4){(_Float16)(a0 - (float)h0), (_Float16)(a1 - (float)h1),
                 (_Float16)(a2 - (float)h2), (_Float16)(a3 - (float)h3)};
}

// prologue: W (f32 [E][D]) -> interleaved [E][g][hi16|lo16] in workspace
__global__ __launch_bounds__(256) void wsplit_kernel(
    const float* __restrict__ W, char* __restrict__ wsp)
{
    const int gid = blockIdx.x * 256 + threadIdx.x;   // 0..16383
    const int e = gid >> 8, g = gid & 255;
    const float4 a = *(const float4*)&W[(size_t)e * DD + g * 8];
    const float4 b = *(const float4*)&W[(size_t)e * DD + g * 8 + 4];
    f16x8 hi, lo;
    split8(a, b, hi, lo);
    char* dst = wsp + (size_t)e * WROWB + g * 32;
    *(f16x8*)dst        = hi;
    *(f16x8*)(dst + 16) = lo;
}

__global__ __launch_bounds__(THREADS, 4) void router_kernel(
    const float* __restrict__ x, const char* __restrict__ wsp,
    const float* __restrict__ bias_g, float* __restrict__ out, int n_tokens)
{
    __shared__ __attribute__((aligned(16))) char  lds[2 * BUFB];        // 52224 B
    __shared__ __attribute__((aligned(16))) float logits[TM * (EE + 1)]; // 8320 B

    const int tid   = threadIdx.x;
    const int tBase = blockIdx.x * TM;

    // ---- staging maps ----
    // W: thread -> row swr (0..63), group swg (0..7); 32B per thread per chunk
    const int swr = tid >> 3;
    const int swg = tid & 7;
    const char* wsrc = wsp + (size_t)swr * WROWB + swg * 32;   // + c*256/chunk
    // x: thread -> row sxr (0..31), f4-col sxg (0..15); 16B per thread per chunk
    const int sxr = tid >> 4;
    const int sxg = tid & 15;
    const float* xsrc = x + (size_t)(tBase + sxr) * DD + sxg * 4;  // + c*BK

    // 4 named register stages (compile-time indices only — no scratch)
    float4 xv0, xv1, xv2, xv3;
    f16x8  wh0, wl0, wh1, wl1, wh2, wl2, wh3, wl3;

#define LOADS(c, xv, wh, wl) { \
    wh = *(const f16x8*)(wsrc + (c) * 256);        \
    wl = *(const f16x8*)(wsrc + (c) * 256 + 16);   \
    xv = *(const float4*)&xsrc[(c) * BK]; }

#define WRITE_STAGE(buf, xv, wh, wl) { \
    char* base = lds + (size_t)(buf) * BUFB; \
    { f16x4 hi, lo; split4(xv, hi, lo); \
      const int off = sxr * ROWB + (sxg >> 1) * 32 + (sxg & 1) * 8; \
      *(f16x4*)(base + off)      = hi; \
      *(f16x4*)(base + off + 16) = lo; } \
    { const int off = XPLANE + swr * ROWB + swg * 32; \
      *(f16x8*)(base + off)      = wh; \
      *(f16x8*)(base + off + 16) = wl; } }

    // ---- MFMA mapping (16x16x32 f16): wave = 16 tokens x 16 experts ----
    const int wv   = tid >> 6;        // wave 0..7
    const int lane = tid & 63;
    const int mt   = wv & 1;          // token tile
    const int nt   = wv >> 1;         // expert tile 0..3
    const int r16  = lane & 15;
    const int kg   = lane >> 4;

    const int aoff = (mt * 16 + r16) * ROWB + kg * 32;
    const int boff = XPLANE + (nt * 16 + r16) * ROWB + kg * 32;

    f32x4 acc = {0.f, 0.f, 0.f, 0.f};

    // 3-product split (skip lo*lo: ~2^-22 rel, verified absmax 0)
#define COMPUTE(buf) { \
    const char* base = lds + (size_t)(buf) * BUFB; \
    _Pragma("unroll") for (int ks = 0; ks < 2; ++ks) { \
        const f16x8 ah = *(const f16x8*)(base + aoff + ks * 128); \
        const f16x8 al = *(const f16x8*)(base + aoff + ks * 128 + 16); \
        const f16x8 bh = *(const f16x8*)(base + boff + ks * 128); \
        const f16x8 bl = *(const f16x8*)(base + boff + ks * 128 + 16); \
        acc = __builtin_amdgcn_mfma_f32_16x16x32_f16(ah, bh, acc, 0, 0, 0); \
        acc = __builtin_amdgcn_mfma_f32_16x16x32_f16(al, bh, acc, 0, 0, 0); \
        acc = __builtin_amdgcn_mfma_f32_16x16x32_f16(ah, bl, acc, 0, 0, 0); \
    } }

    // ---- pipeline: 4-deep prefetch, 1 lgkm-barrier/chunk, vmcnt uncounted --
    // chunk m lives in reg set m&3; loads for c+3 issue at body c (2 chunks
    // of slack before WRITE_STAGE consumes them at body c+2).
    LOADS(0, xv0, wh0, wl0);
    WRITE_STAGE(0, xv0, wh0, wl0);
    LOADS(1, xv1, wh1, wl1);
    LOADS(2, xv2, wh2, wl2);

    for (int i = 0; i < NCHUNK; i += 4) {
        BARRIER();                                        // chunk i in buf0
        if (i + 3 < NCHUNK) LOADS(i + 3, xv3, wh3, wl3);
        COMPUTE(0);
        if (i + 1 < NCHUNK) WRITE_STAGE(1, xv1, wh1, wl1);

        BARRIER();                                        // chunk i+1 in buf1
        if (i + 4 < NCHUNK) LOADS(i + 4, xv0, wh0, wl0);
        COMPUTE(1);
        if (i + 2 < NCHUNK) WRITE_STAGE(0, xv2, wh2, wl2);

        BARRIER();                                        // chunk i+2 in buf0
        if (i + 5 < NCHUNK) LOADS(i + 5, xv1, wh1, wl1);
        COMPUTE(0);
        if (i + 3 < NCHUNK) WRITE_STAGE(1, xv3, wh3, wl3);

        BARRIER();                                        // chunk i+3 in buf1
        if (i + 6 < NCHUNK) LOADS(i + 6, xv2, wh2, wl2);
        COMPUTE(1);
        if (i + 4 < NCHUNK) WRITE_STAGE(0, xv0, wh0, wl0);
    }

    // ---- epilogue: unscale (acc = 1024 * logit), add bias, top-2 ----
    const int col  = nt * 16 + r16;
    const float bcol = bias_g[col];
    const float INV  = 1.f / 1024.f;
    const int rbase  = mt * 16 + kg * 4;
#pragma unroll
    for (int r = 0; r < 4; ++r)
        logits[(rbase + r) * (EE + 1) + col] = acc[r] * INV + bcol;
    __syncthreads();

    if (tid < TM) {
        const float* lrow = &logits[tid * (EE + 1)];
        float v1 = -INFINITY, v2 = -INFINITY;
        int   i1 = 0, i2 = 0;
        for (int e = 0; e < EE; ++e) {
            const float v = lrow[e];
            if (v > v1) { v2 = v1; i2 = i1; v1 = v; i1 = e; }
            else if (v > v2) { v2 = v; i2 = e; }
        }
        const float ed  = expf(v2 - v1);
        const float inv = 1.f / (1.f + ed);
        const int tok = tBase + tid;
        out[tok * 2 + 0] = inv;
        out[tok * 2 + 1] = ed * inv;
        float* oidx = out + (size_t)2 * n_tokens;
        oidx[tok * 2 + 0] = (float)i1;
        oidx[tok * 2 + 1] = (float)i2;
    }
}

extern "C" void kernel_launch(void* const* d_in, const int* in_sizes, int n_in,
                              void* d_out, int out_size, void* d_ws, size_t ws_size,
                              hipStream_t stream) {
    const float* x = (const float*)d_in[0];
    const float* W = (const float*)d_in[1];
    const float* b = (const float*)d_in[2];
    float* out = (float*)d_out;

    const int n_tokens = in_sizes[0] / DD;      // 16384
    const int n_blocks = n_tokens / TM;         // 512

    char* wsp = (char*)d_ws;                    // 512 KB W split planes

    wsplit_kernel<<<(EE * DD / 8) / 256, 256, 0, stream>>>(W, wsp);
    router_kernel<<<n_blocks, THREADS, 0, stream>>>(x, wsp, b, out, n_tokens);
}